// Round 8
// baseline (171.559 us; speedup 1.0000x reference)
//
#include <hip/hip_runtime.h>

// Skeleton forward kinematics: angles [B,16,6] f32, xyz [1,16,3] f32 -> out [B,16,3] f32.
// R11: TEMPORAL PIPELINING, 2 ELEMENTS/THREAD. Evidence chain (per-dispatch times):
//   R3 64.5us (uncoal ld/st, VGPR132) | R6 65us (coal ST via LDS: NULL) | R9 64.5us
//   (occ 10->23%: NULL) | R10 61us (coal LD via LDS: ~NULL) | R5/R8: spill runs
//   sustained 2.7-3.15 TB/s -> chip streams fine when traffic is CONTINUOUS.
//   All ~61-65us variants share ONE trait: burst loads at wave start -> long silent
//   compute -> trickle stores, with block waves in lockstep (bursts correlated).
//   Memory idles most of each wave's life; each wave generation pays full exposed
//   fill latency. Fix: issue BOTH elements' loads up front (48 float4), chain elem0
//   while elem1's fills land, then chain elem1. Grid 512 blocks = 2 blocks/CU =
//   single wave generation; exposed latency paid once per dispatch, not per round.
//   Loads uncoalesced (R10: coalescing null), stores scalar (R6: null), no LDS,
//   NO __launch_bounds__ min-waves (R5/R8: allocator collapse). Peak ~240 VGPR OK.
//   Tripwire: FETCH>>50MB or WRITE>>64MB => scratch spill => shrink pipeline depth.

namespace {

constexpr int NJ = 16;

__device__ __forceinline__ void rot6d(const float* __restrict__ a, float R[9]) {
    float inv1 = rsqrtf(a[0]*a[0] + a[1]*a[1] + a[2]*a[2]);
    float b10 = a[0]*inv1, b11 = a[1]*inv1, b12 = a[2]*inv1;
    float d = b10*a[3] + b11*a[4] + b12*a[5];
    float c0 = a[3] - d*b10, c1 = a[4] - d*b11, c2 = a[5] - d*b12;
    float inv2 = rsqrtf(c0*c0 + c1*c1 + c2*c2);
    float b20 = c0*inv2, b21 = c1*inv2, b22 = c2*inv2;
    R[0] = b10; R[1] = b11; R[2] = b12;
    R[3] = b20; R[4] = b21; R[5] = b22;
    R[6] = b11*b22 - b12*b21;
    R[7] = b12*b20 - b10*b22;
    R[8] = b10*b21 - b11*b20;
}

// Full 16-joint chain for one element; af = 96 angle floats, ob = 48 output floats.
__device__ __forceinline__ void run_chain(const float* __restrict__ af,
                                          const float* __restrict__ xyz,
                                          float* __restrict__ ob) {
    float R[9], Rw[9], pw[3], Rw3[9], pw3[3];

    // ---- joint 0 ----
    rot6d(&af[0], Rw);
    {
        float x = xyz[0], y = xyz[1], z = xyz[2];
        pw[0] = Rw[0]*x + Rw[1]*y + Rw[2]*z;
        pw[1] = Rw[3]*x + Rw[4]*y + Rw[5]*z;
        pw[2] = Rw[6]*x + Rw[7]*y + Rw[8]*z;
    }
    ob[0] = pw[0]; ob[1] = pw[1]; ob[2] = pw[2];

    // tree edges (child = e+1); chains 0-1-2-3, 3-4-5, 3-6..10, 3-11..15
    constexpr int PAR[15] = {0, 1, 2, 3, 4, 3, 6, 7, 8, 9, 3, 11, 12, 13, 14};

#pragma unroll
    for (int e = 0; e < 15; ++e) {
        const int c = e + 1;
        const int p = PAR[e];

        if (p == 3) {  // branch restart: restore saved state at joint 3
#pragma unroll
            for (int k = 0; k < 9; ++k) Rw[k] = Rw3[k];
            pw[0] = pw3[0]; pw[1] = pw3[1]; pw[2] = pw3[2];
        }

        rot6d(&af[c * 6], R);

        // t = ref[c] - ref[p] (wave-uniform scalar loads, hoisted to SGPRs)
        float tx = xyz[c * 3 + 0] - xyz[p * 3 + 0];
        float ty = xyz[c * 3 + 1] - xyz[p * 3 + 1];
        float tz = xyz[c * 3 + 2] - xyz[p * 3 + 2];

        // local_t = R @ t
        float lt0 = R[0]*tx + R[1]*ty + R[2]*tz;
        float lt1 = R[3]*tx + R[4]*ty + R[5]*tz;
        float lt2 = R[6]*tx + R[7]*ty + R[8]*tz;

        // pw[c] = Rw[p] @ local_t + pw[p]
        float np0 = Rw[0]*lt0 + Rw[1]*lt1 + Rw[2]*lt2 + pw[0];
        float np1 = Rw[3]*lt0 + Rw[4]*lt1 + Rw[5]*lt2 + pw[1];
        float np2 = Rw[6]*lt0 + Rw[7]*lt1 + Rw[8]*lt2 + pw[2];

        // Rw[c] = Rw[p] @ R[c]
        float T[9];
#pragma unroll
        for (int i = 0; i < 3; ++i)
#pragma unroll
            for (int j = 0; j < 3; ++j)
                T[i*3 + j] = Rw[i*3 + 0]*R[0*3 + j]
                           + Rw[i*3 + 1]*R[1*3 + j]
                           + Rw[i*3 + 2]*R[2*3 + j];
#pragma unroll
        for (int k = 0; k < 9; ++k) Rw[k] = T[k];
        pw[0] = np0; pw[1] = np1; pw[2] = np2;

        // store immediately (fire-and-forget)
        ob[c*3 + 0] = np0; ob[c*3 + 1] = np1; ob[c*3 + 2] = np2;

        if (c == 3) {  // save branch point (children 4, 6, 11)
#pragma unroll
            for (int k = 0; k < 9; ++k) Rw3[k] = Rw[k];
            pw3[0] = pw[0]; pw3[1] = pw[1]; pw3[2] = pw[2];
        }
    }
}

__global__ __launch_bounds__(256) void skel_kernel(
    const float* __restrict__ angles,
    const float* __restrict__ xyz,
    float* __restrict__ out,
    int batch)
{
    const int tid = threadIdx.x;
    const int b0 = blockIdx.x * 512 + tid;
    const int b1 = b0 + 256;
    if (b0 >= batch) return;              // (batch = 512*512: no partial blocks, guard cheap)
    const bool has1 = (b1 < batch);

    const float4* a0 = (const float4*)(angles + (size_t)b0 * (NJ * 6));
    const float4* a1 = (const float4*)(angles + (size_t)b1 * (NJ * 6));

    // ---- issue BOTH elements' loads up front: 48 independent float4 ----
    float4 v[24];
#pragma unroll
    for (int k = 0; k < 24; ++k) v[k] = a0[k];
    float4 w[24];
    if (has1) {
#pragma unroll
        for (int k = 0; k < 24; ++k) w[k] = a1[k];
    }
    // Fence: no load may sink into the dependent chains below.
    __builtin_amdgcn_sched_barrier(0);

    // repack elem0 (compiler waits only on v's fills; w stays in flight)
    float af0[NJ * 6];
#pragma unroll
    for (int k = 0; k < 24; ++k) {
        af0[4*k + 0] = v[k].x; af0[4*k + 1] = v[k].y;
        af0[4*k + 2] = v[k].z; af0[4*k + 3] = v[k].w;
    }

    // chain elem0 — w's HBM latency hides under this (~3-6k cy)
    run_chain(af0, xyz, out + (size_t)b0 * (NJ * 3));

    if (has1) {
        float af1[NJ * 6];
#pragma unroll
        for (int k = 0; k < 24; ++k) {
            af1[4*k + 0] = w[k].x; af1[4*k + 1] = w[k].y;
            af1[4*k + 2] = w[k].z; af1[4*k + 3] = w[k].w;
        }
        run_chain(af1, xyz, out + (size_t)b1 * (NJ * 3));
    }
}

} // namespace

extern "C" void kernel_launch(void* const* d_in, const int* in_sizes, int n_in,
                              void* d_out, int out_size, void* d_ws, size_t ws_size,
                              hipStream_t stream) {
    const float* angles = (const float*)d_in[0];   // [B, 16, 6] f32
    const float* xyz    = (const float*)d_in[1];   // [1, 16, 3] f32
    float* out          = (float*)d_out;           // [B, 16, 3] f32

    const int batch = in_sizes[0] / (NJ * 6);
    dim3 grid((batch + 511) / 512);
    skel_kernel<<<grid, 256, 0, stream>>>(angles, xyz, out, batch);
}